// Round 18
// baseline (171.073 us; speedup 1.0000x reference)
//
#include <hip/hip_runtime.h>
#include <hip/hip_bf16.h>
#include <stdint.h>

#define N_ 160
#define B_ 16
#define C_ 64
#define S_ 80
#define TWO_C 128
#define BNN (B_*N_*N_)     // 409600 rows
#define ROWS_BN (B_*N_)    // 2560
#define RPB 8              // rows per k_fused block (2->91us, 4->87.4us; try 8)

typedef unsigned short u16;
using frag_ab = __attribute__((ext_vector_type(8))) short;   // 8 bf16
using frag_cd = __attribute__((ext_vector_type(4))) float;   // 4 f32

// hand-rolled RNE f32->bf16 — FASTER than native __float2bfloat16 on this
// kernel (r12 vs r13 A/B: 117 vs 149 us). Do not "modernize".
__device__ __forceinline__ u16 f2bf(float f) {
    union { float f; uint32_t u; } v; v.f = f;
    uint32_t u = v.u;
    return (u16)((u + 0x7FFFu + ((u >> 16) & 1u)) >> 16);
}
__device__ __forceinline__ float bf2f(u16 h) {
    union { uint32_t u; float f; } v; v.u = ((uint32_t)h) << 16;
    return v.f;
}
__device__ __forceinline__ float lrelu(float x) { return x >= 0.f ? x : 0.01f * x; }

// ---------------- closed-form BN1 stats: moments of v (BOTH calls) -----------
// k_prep folded into the first 64 blocks (w1/w2 -> bf16).
__global__ __launch_bounds__(256)
void k_mom(const float* __restrict__ v0, const float* __restrict__ v1,
           float* __restrict__ mom, float* __restrict__ s1p, float* __restrict__ s2p,
           const float* __restrict__ w1, const float* __restrict__ w2,
           u16* __restrict__ w1b, u16* __restrict__ w2b) {
    __shared__ __align__(16) float vl[32][64];
    const int gbid = blockIdx.x;
    const int call = gbid / 320;
    const int bid  = gbid % 320;
    const int ic  = bid % 5;
    const int c1g = (bid / 5) % 4;
    const int b   = bid / 20;
    const int t = threadIdx.x;
    if (gbid < 64) {                       // folded k_prep: 16384 converts
        int i = gbid * 256 + t;
        if (i < TWO_C * C_) w1b[i] = f2bf(w1[i]);
        else                w2b[i - TWO_C * C_] = f2bf(w2[i - TWO_C * C_]);
    }
    const float* v = call ? v1 : v0;
    const float* src = v + ((size_t)b * N_ + ic * 32) * C_;
    #pragma unroll
    for (int p = 0; p < 2; p++) {
        int idx = t + p * 256;
        *reinterpret_cast<float4*>(&vl[0][0] + (size_t)idx * 4) =
            *reinterpret_cast<const float4*>(src + (size_t)idx * 4);
    }
    __syncthreads();
    const int c1 = c1g * 16 + (t >> 4);
    const int c2b = (t & 15) * 4;
    float m2[4] = {0,0,0,0}, m21[4] = {0,0,0,0}, m22[4] = {0,0,0,0};
    for (int i = 0; i < 32; i++) {
        float x1 = vl[i][c1];
        #pragma unroll
        for (int q = 0; q < 4; q++) {
            float x2 = vl[i][c2b + q];
            float tt = x1 * x2;
            m2[q]  += tt;
            m21[q] += x1 * tt;
            m22[q] += tt * tt;
        }
    }
    const int pl = (t >> 4) * 64 + c2b;
    float* base = mom + (size_t)gbid * 3072;
    *reinterpret_cast<float4*>(base + pl)        = *reinterpret_cast<float4*>(m2);
    *reinterpret_cast<float4*>(base + 1024 + pl) = *reinterpret_cast<float4*>(m21);
    *reinterpret_cast<float4*>(base + 2048 + pl) = *reinterpret_cast<float4*>(m22);
    if (c1g == 0 && t < 64) {
        float s1 = 0.f, s2 = 0.f;
        for (int i = 0; i < 32; i++) { float x = vl[i][t]; s1 += x; s2 += x * x; }
        s1p[(size_t)(call * 80 + b * 5 + ic) * 64 + t] = s1;
        s2p[(size_t)(call * 80 + b * 5 + ic) * 64 + t] = s2;
    }
}

// S[c1,c2] + T1, both calls. grid 512 = call(2) x 256.
__global__ __launch_bounds__(256)
void k_S(const float* __restrict__ mom, const float* __restrict__ s1p,
         const float* __restrict__ s2p, float* __restrict__ Ssum,
         float* __restrict__ T1) {
    __shared__ float red[256];
    const int t = threadIdx.x;
    const int call = blockIdx.x / 256;
    const int lb = blockIdx.x % 256;
    const int pl = t >> 4, b = t & 15;
    const int pi = lb * 16 + pl;
    const int c1 = pi >> 6, c2 = pi & 63;
    const float* momc = mom + (size_t)call * 320 * 3072;
    const float* s1c = s1p + (size_t)call * 80 * 64;
    const float* s2c = s2p + (size_t)call * 80 * 64;
    const int bidA = (b * 4 + (c1 >> 4)) * 5;
    const int plA  = (c1 & 15) * 64 + c2;
    const int bidB = (b * 4 + (c2 >> 4)) * 5;
    const int plB  = (c2 & 15) * 64 + c1;
    float m2 = 0.f, m21 = 0.f, m22 = 0.f, m21T = 0.f;
    float s1c1 = 0.f, s1c2 = 0.f, s2c1 = 0.f, s2c2 = 0.f;
    #pragma unroll
    for (int ic = 0; ic < 5; ic++) {
        const float* base = momc + (size_t)(bidA + ic) * 3072;
        m2   += base[plA];
        m21  += base[1024 + plA];
        m22  += base[2048 + plA];
        m21T += momc[(size_t)(bidB + ic) * 3072 + 1024 + plB];
        s1c1 += s1c[(size_t)(b * 5 + ic) * 64 + c1];
        s1c2 += s1c[(size_t)(b * 5 + ic) * 64 + c2];
        s2c1 += s2c[(size_t)(b * 5 + ic) * 64 + c1];
        s2c2 += s2c[(size_t)(b * 5 + ic) * 64 + c2];
    }
    float S = 2.f*(float)N_*m22 + 2.f*s2c1*s2c2 + 4.f*m2*m2
            - 4.f*m21*s1c2 - 4.f*m21T*s1c1;
    red[t] = S; __syncthreads();
    #pragma unroll
    for (int off = 8; off; off >>= 1) {
        if (b < off) red[t] += red[t + off];
        __syncthreads();
    }
    if (b == 0) Ssum[call * 4096 + pi] = red[t];
    if (lb < 4) {
        float tv = 2.f*(float)N_*s2c2 - 2.f*s1c2*s1c2;
        __syncthreads();
        red[t] = tv; __syncthreads();
        #pragma unroll
        for (int off = 8; off; off >>= 1) {
            if (b < off) red[t] += red[t + off];
            __syncthreads();
        }
        if (b == 0) T1[call * 64 + pi] = red[t];
    }
}

// per-o BN1 constants, both calls. grid 256 = call(2) x o(128).
__global__ __launch_bounds__(64)
void k_bn1const(const float* __restrict__ Ssum, const float* __restrict__ T1,
                const float* __restrict__ w1, const float* __restrict__ g1,
                const float* __restrict__ b1, float* __restrict__ c1c) {
    const int call = blockIdx.x >> 7;
    const int o = blockIdx.x & 127;
    const int c1 = threadIdx.x;
    const float* Ss = Ssum + call * 4096;
    const float* T1c = T1 + call * 64;
    const float* wrow = w1 + (size_t)o * 64;
    float wc1 = wrow[c1];
    float acc = 0.f;
    for (int c2 = 0; c2 < 64; c2++)
        acc += wrow[c2] * Ss[c1 * 64 + c2];
    float qf = wc1 * acc;
    float mn = wc1 * T1c[c1];
    #pragma unroll
    for (int off = 32; off; off >>= 1) {
        qf += __shfl_xor(qf, off, 64);
        mn += __shfl_xor(mn, off, 64);
    }
    if (c1 == 0) {
        const float inv = 1.f / (float)BNN;
        float mean = mn * inv;
        float var  = qf * inv - mean * mean;
        float a = g1[o] * rsqrtf(var + 1e-5f);
        c1c[call * 256 + o] = a;
        c1c[call * 256 + 128 + o] = b1[o] - mean * a;
    }
}

// ---------------- fused heavy stage: r12 inner structure, RPB rows per block -
// grid = 2*ROWS_BN/RPB. Inner 3-barrier j-tile loop is the verified r12
// pipeline; outer rr loop amortizes bfrag/c1c setup RPB x and divides the
// block-cohort count. Pending-store keeps store/compute overlap across row
// boundaries (same 2-barrier hazard separation). Row octets stay in one batch.
__global__ __launch_bounds__(256)
void k_fused(const float* __restrict__ v0, const float* __restrict__ v1,
             const u16* __restrict__ w1b, const float* __restrict__ c1c_all,
             const u16* __restrict__ w2b, u16* __restrict__ z2b_all,
             float* __restrict__ partials_all) {
    __shared__ __align__(16) u16 simT[32 * 64];
    __shared__ __align__(16) u16 h1T[32 * 128];
    __shared__ __align__(16) u16 z2T[32 * 64];
    __shared__ float sb_s[4][64];
    __shared__ float sb_ss[4][64];
    const int gbid = blockIdx.x;
    const int call = gbid / (ROWS_BN / RPB);
    const int ri0 = (gbid % (ROWS_BN / RPB)) * RPB;
    const float* __restrict__ v = call ? v1 : v0;
    const float* __restrict__ c1c = c1c_all + call * 256;
    u16* __restrict__ z2b = z2b_all + (size_t)call * BNN * C_;
    float* __restrict__ partials = partials_all;  // indexed by gbid

    const int t = threadIdx.x;
    const int bb = ri0 / N_;
    const int w = t >> 6, lane = t & 63;
    const int l15 = lane & 15, kgrp = lane >> 4, k0 = kgrp * 8;
    const int jt16 = w & 1;           // GEMM1 row-half
    const int rh = w >> 1, q = w & 1; // GEMM2 row-half / col-half
    const int obase = rh * 64;        // GEMM1 o-quadrant

    const int jj = t >> 3, c0 = (t & 7) * 8;
    const float* __restrict__ vrow = v + (size_t)bb * N_ * C_;

    frag_ab bfrag[4][2];
    float cAr[4], cBr[4];
    #pragma unroll
    for (int tt = 0; tt < 4; tt++) {
        int o = obase + tt * 16 + l15;
        #pragma unroll
        for (int kk = 0; kk < 2; kk++)
            bfrag[tt][kk] = *reinterpret_cast<const frag_ab*>(w1b + o * 64 + kk * 32 + k0);
        cAr[tt] = c1c[o];
        cBr[tt] = c1c[128 + o];
    }

    float s_l[2] = {0.f, 0.f}, ss_l[2] = {0.f, 0.f};
    size_t pend_rowb = 0;
    bool pend = false;

    for (int rr = 0; rr < RPB; rr++) {
        const int ri = ri0 + rr;
        const float* __restrict__ vi = v + (size_t)ri * C_;
        float fi[8] __attribute__((aligned(16)));
        *reinterpret_cast<float4*>(&fi[0]) = *reinterpret_cast<const float4*>(vi + c0);
        *reinterpret_cast<float4*>(&fi[4]) = *reinterpret_cast<const float4*>(vi + c0 + 4);
        float fj[8] __attribute__((aligned(16)));
        {
            const float* vj = vrow + (size_t)jj * C_ + c0;
            *reinterpret_cast<float4*>(&fj[0]) = *reinterpret_cast<const float4*>(vj);
            *reinterpret_cast<float4*>(&fj[4]) = *reinterpret_cast<const float4*>(vj + 4);
        }

        for (int jt = 0; jt < 5; jt++) {
            // ---- P1: coalesced store of pending z2 tile + build sim tile ----
            if (pend) {
                int idx = (jj * 64 + c0) ^ ((jj & 7) << 3);
                frag_ab zz = *reinterpret_cast<const frag_ab*>(&z2T[idx]);
                *reinterpret_cast<frag_ab*>(z2b + (pend_rowb + jj) * C_ + c0) = zz;
            }
            {
                frag_ab pack;
                #pragma unroll
                for (int p8 = 0; p8 < 8; p8++) {
                    float d = fi[p8] - fj[p8];
                    pack[p8] = (short)f2bf(d * d);
                }
                int idx = (jj * 64 + c0) ^ ((jj & 7) << 3);
                *reinterpret_cast<frag_ab*>(&simT[idx]) = pack;
            }
            __syncthreads();                                   // bar1

            // ---- P2: GEMM1 + BN1/lrelu pack -> h1T ----
            frag_cd acc1[4];
            #pragma unroll
            for (int tt = 0; tt < 4; tt++) acc1[tt] = frag_cd{0.f, 0.f, 0.f, 0.f};
            #pragma unroll
            for (int kk = 0; kk < 2; kk++) {
                const int rj = jt16 * 16 + l15;
                const int idx = (rj * 64 + kk * 32 + k0) ^ ((rj & 7) << 3);
                frag_ab a = *reinterpret_cast<const frag_ab*>(&simT[idx]);
                #pragma unroll
                for (int tt = 0; tt < 4; tt++)
                    acc1[tt] = __builtin_amdgcn_mfma_f32_16x16x32_bf16(a, bfrag[tt][kk], acc1[tt], 0, 0, 0);
            }
            #pragma unroll
            for (int tt = 0; tt < 4; tt++) {
                const int o = obase + tt * 16 + l15;
                #pragma unroll
                for (int r = 0; r < 4; r++) {
                    const int row = jt16 * 16 + kgrp * 4 + r;
                    float hv = lrelu(acc1[tt][r] * cAr[tt] + cBr[tt]);
                    h1T[(row * 128 + o) ^ ((row & 7) << 3)] = f2bf(hv);
                }
            }
            __syncthreads();                                   // bar2

            // ---- P3: prefetch next fj, GEMM2, pack z2T, stats ----
            if (jt < 4) {
                const float* vj = vrow + ((size_t)(jt + 1) * 32 + jj) * C_ + c0;
                *reinterpret_cast<float4*>(&fj[0]) = *reinterpret_cast<const float4*>(vj);
                *reinterpret_cast<float4*>(&fj[4]) = *reinterpret_cast<const float4*>(vj + 4);
            }
            frag_cd acc2[2];
            acc2[0] = frag_cd{0.f,0.f,0.f,0.f}; acc2[1] = frag_cd{0.f,0.f,0.f,0.f};
            #pragma unroll
            for (int kk = 0; kk < 4; kk++) {
                const int rrr = rh * 16 + l15;
                const int idx = (rrr * 128 + kk * 32 + k0) ^ ((rrr & 7) << 3);
                frag_ab a = *reinterpret_cast<const frag_ab*>(&h1T[idx]);
                #pragma unroll
                for (int tt = 0; tt < 2; tt++) {
                    const int p = q * 32 + tt * 16 + l15;
                    frag_ab bfr = *reinterpret_cast<const frag_ab*>(w2b + (size_t)p * 128 + kk * 32 + k0);
                    acc2[tt] = __builtin_amdgcn_mfma_f32_16x16x32_bf16(a, bfr, acc2[tt], 0, 0, 0);
                }
            }
            #pragma unroll
            for (int tt = 0; tt < 2; tt++) {
                const int p = q * 32 + tt * 16 + l15;
                #pragma unroll
                for (int r = 0; r < 4; r++) {
                    const int row = rh * 16 + kgrp * 4 + r;
                    float val = acc2[tt][r];
                    z2T[(row * 64 + p) ^ ((row & 7) << 3)] = f2bf(val);
                    s_l[tt] += val; ss_l[tt] += val * val;
                }
            }
            pend_rowb = (size_t)ri * N_ + (size_t)jt * 32;
            pend = true;
            __syncthreads();                                   // bar3
        }
    }

    // ---- epilogue: store last z2 tile ----
    {
        int idx = (jj * 64 + c0) ^ ((jj & 7) << 3);
        frag_ab zz = *reinterpret_cast<const frag_ab*>(&z2T[idx]);
        *reinterpret_cast<frag_ab*>(z2b + (pend_rowb + jj) * C_ + c0) = zz;
    }
    // ---- stats reduce -> per-block contiguous partials (indexed by gbid) ----
    #pragma unroll
    for (int tt = 0; tt < 2; tt++) {
        s_l[tt]  += __shfl_xor(s_l[tt], 16, 64);  s_l[tt]  += __shfl_xor(s_l[tt], 32, 64);
        ss_l[tt] += __shfl_xor(ss_l[tt], 16, 64); ss_l[tt] += __shfl_xor(ss_l[tt], 32, 64);
    }
    if (lane < 16) {
        #pragma unroll
        for (int tt = 0; tt < 2; tt++) {
            const int p = q * 32 + tt * 16 + l15;
            sb_s[w][p]  = s_l[tt];
            sb_ss[w][p] = ss_l[tt];
        }
    }
    __syncthreads();
    if (t < 64) {
        const int qq = t >> 5;
        partials[(size_t)gbid * 128 + t]      = sb_s[qq][t]  + sb_s[qq + 2][t];
        partials[(size_t)gbid * 128 + 64 + t] = sb_ss[qq][t] + sb_ss[qq + 2][t];
    }
}

// reduce partials + BN2 consts, both calls: grid 128 = call(2) x c(64)
// partials are per-k_fused-block (ROWS_BN/RPB blocks per call).
__global__ __launch_bounds__(256)
void k_reduce_bn2(const float* __restrict__ partials_all, const float* __restrict__ g2,
                  const float* __restrict__ b2, float* __restrict__ c2c) {
    const int call = blockIdx.x >> 6;
    const int c = blockIdx.x & 63;
    const int t = threadIdx.x;
    const float* partials = partials_all + (size_t)call * (ROWS_BN / RPB) * 128;
    float s = 0.f, ss = 0.f;
    for (int b = t; b < ROWS_BN / RPB; b += 256) {
        s  += partials[(size_t)b * 128 + c];
        ss += partials[(size_t)b * 128 + 64 + c];
    }
    __shared__ float l1[256], l2[256];
    l1[t] = s; l2[t] = ss; __syncthreads();
    for (int off = 128; off; off >>= 1) {
        if (t < off) { l1[t] += l1[t + off]; l2[t] += l2[t + off]; }
        __syncthreads();
    }
    if (t == 0) {
        const float inv = 1.f / (float)BNN;
        float mean = l1[0] * inv;
        float var  = l2[0] * inv - mean * mean;
        float a = g2[c] * rsqrtf(var + 1e-5f);
        c2c[call * 128 + c] = a;
        c2c[call * 128 + 64 + c] = b2[c] - mean * a;
    }
}

// ---------------- ONE tail kernel: e0,e1 (parallel) + edge chain + p2d -------
__device__ __forceinline__ float block_sum(float v, float* lds) {
    #pragma unroll
    for (int off = 32; off; off >>= 1) v += __shfl_xor(v, off, 64);
    __syncthreads();
    if ((threadIdx.x & 63) == 0) lds[threadIdx.x >> 6] = v;
    __syncthreads();
    return lds[0] + lds[1] + lds[2] + lds[3];
}
__device__ __forceinline__ float edge_renorm(float e, float ep, bool diag, bool valid,
                                             float* lds4) {
    float epm = diag ? 0.f : ep;
    float rs = block_sum(epm, lds4);
    float x = e * epm;
    float s = block_sum(fabsf(x), lds4);
    x = x / fmaxf(s, 1e-12f) * rs;
    x += (diag ? 1.f : 0.f) + 1e-6f;
    float tot = block_sum(valid ? x : 0.f, lds4);
    return x / tot;
}

__global__ __launch_bounds__(256)
void k_tail(const u16* __restrict__ z2b_all, const float* __restrict__ c2c,
            const float* __restrict__ w3, const float* __restrict__ b3,
            const float* __restrict__ pedge, const float* __restrict__ dnode,
            const float* __restrict__ p2dw, const float* __restrict__ p2db,
            float* __restrict__ out0, float* __restrict__ out1) {
    __shared__ float cs[320];          // c2c[0..255] | w3[256..319]
    __shared__ float e0l[N_], e1l[N_];
    __shared__ float lds4[4];
    __shared__ float xl[2 * S_];
    const int r = blockIdx.x;          // b*N + i
    const int t = threadIdx.x;
    const float bb3 = b3[0];

    cs[t] = (t < 256) ? c2c[t] : 0.f;
    if (t < 64) cs[256 + t] = w3[t];
    __syncthreads();

    // ---- phase A: e0/e1 rows, 8 threads per j, 32 j per pass ----
    const int jloc = t >> 3, cA0 = (t & 7) * 8;
    #pragma unroll
    for (int pass = 0; pass < 5; pass++) {
        const int j = pass * 32 + jloc;
        const u16* zr0 = z2b_all + ((size_t)r * N_ + j) * C_ + cA0;
        const u16* zr1 = zr0 + (size_t)BNN * C_;
        frag_ab z0 = *reinterpret_cast<const frag_ab*>(zr0);
        frag_ab z1 = *reinterpret_cast<const frag_ab*>(zr1);
        float a0 = 0.f, a1 = 0.f;
        #pragma unroll
        for (int qi = 0; qi < 8; qi++) {
            const int c = cA0 + qi;
            a0 += lrelu(bf2f((u16)z0[qi]) * cs[c]       + cs[64 + c])  * cs[256 + c];
            a1 += lrelu(bf2f((u16)z1[qi]) * cs[128 + c] + cs[192 + c]) * cs[256 + c];
        }
        a0 += __shfl_xor(a0, 1, 64); a0 += __shfl_xor(a0, 2, 64); a0 += __shfl_xor(a0, 4, 64);
        a1 += __shfl_xor(a1, 1, 64); a1 += __shfl_xor(a1, 2, 64); a1 += __shfl_xor(a1, 4, 64);
        if ((t & 7) == 0) {
            e0l[j] = 1.f / (1.f + __expf(-(a0 + bb3)));
            e1l[j] = 1.f / (1.f + __expf(-(a1 + bb3)));
        }
    }
    __syncthreads();

    // ---- phase B: edge chain + p2d (row-local) ----
    const bool valid = t < N_;
    const int iLoc = r % N_;
    const bool diag = (t == iLoc);
    float e0 = valid ? e0l[t] : 0.f;
    float e1 = valid ? e1l[t] : 0.f;
    float pedge_v = valid ? pedge[(size_t)r * N_ + t] : 0.f;

    float pe0 = edge_renorm(e0, pedge_v, diag, valid, lds4);   // initial edge
    float pe1 = edge_renorm(e1, pe0,     diag, valid, lds4);   // gen0 edge

    __syncthreads();
    if (t < S_) { xl[t] = pe1; xl[S_ + t] = dnode[(size_t)r * S_ + t]; }
    __syncthreads();
    float dn1 = 0.f;
    if (t < S_) {
        float acc = p2db[t];
        const float* wr = p2dw + (size_t)t * (2 * S_);
        #pragma unroll 4
        for (int k = 0; k < 2 * S_; k++) acc += xl[k] * wr[k];
        dn1 = lrelu(acc);
        out0[(size_t)r * S_ + t] = dn1;
    }

    float pe2 = edge_renorm(e1, pe1, diag, valid, lds4);       // gen1 edge

    __syncthreads();
    if (t < S_) { xl[t] = pe2; xl[S_ + t] = dn1; }
    __syncthreads();
    if (t < S_) {
        float acc = p2db[S_ + t];
        const float* wr = p2dw + (size_t)(S_ + t) * (2 * S_);
        #pragma unroll 4
        for (int k = 0; k < 2 * S_; k++) acc += xl[k] * wr[k];
        out1[(size_t)r * S_ + t] = lrelu(acc);
    }
}

// ---------------- launch -----------------------------------------------------
extern "C" void kernel_launch(void* const* d_in, const int* in_sizes, int n_in,
                              void* d_out, int out_size, void* d_ws, size_t ws_size,
                              hipStream_t stream) {
    const float* middle = (const float*)d_in[0];
    const float* point  = (const float*)d_in[1];
    const float* dnode  = (const float*)d_in[2];
    // d_in[3] = distribution_edge: unused by the reference forward
    const float* pedge  = (const float*)d_in[4];
    const float* w1 = (const float*)d_in[5];
    const float* g1 = (const float*)d_in[6];
    const float* b1 = (const float*)d_in[7];
    const float* w2 = (const float*)d_in[8];
    const float* g2 = (const float*)d_in[9];
    const float* b2 = (const float*)d_in[10];
    const float* w3 = (const float*)d_in[11];
    const float* b3 = (const float*)d_in[12];
    const float* p2dw = (const float*)d_in[13];
    const float* p2db = (const float*)d_in[14];

    float* out0 = (float*)d_out;
    float* out1 = out0 + (size_t)ROWS_BN * S_;

    char* ws = (char*)d_ws;
    size_t off = 0;
    auto alloc = [&](size_t bytes) -> char* {
        char* p = ws + off;
        off += (bytes + 255) & ~(size_t)255;
        return p;
    };
    u16*   z2b      = (u16*)  alloc((size_t)2 * BNN * C_ * 2);       // 104.9 MB
    u16*   w1b      = (u16*)  alloc(TWO_C * C_ * 2);
    u16*   w2b      = (u16*)  alloc(C_ * TWO_C * 2);
    float* partials = (float*)alloc((size_t)(2 * ROWS_BN / RPB) * 128 * 4);
    float* mom      = (float*)alloc((size_t)2 * 320 * 3072 * 4);     // 7.86 MB
    float* s1p      = (float*)alloc((size_t)2 * 80 * 64 * 4);
    float* s2p      = (float*)alloc((size_t)2 * 80 * 64 * 4);
    float* Ssum     = (float*)alloc(2 * 4096 * 4);
    float* T1       = (float*)alloc(2 * 64 * 4);
    float* c1c      = (float*)alloc(2 * 256 * 4);
    float* c2c      = (float*)alloc(2 * 128 * 4);

    // call0 = middle_node, call1 = point_node; e(point) reused for both gens.
    k_mom<<<640, 256, 0, stream>>>(middle, point, mom, s1p, s2p, w1, w2, w1b, w2b);
    k_S<<<512, 256, 0, stream>>>(mom, s1p, s2p, Ssum, T1);
    k_bn1const<<<256, 64, 0, stream>>>(Ssum, T1, w1, g1, b1, c1c);
    k_fused<<<2 * ROWS_BN / RPB, 256, 0, stream>>>(middle, point, w1b, c1c, w2b, z2b, partials);
    k_reduce_bn2<<<128, 256, 0, stream>>>(partials, g2, b2, c2c);
    k_tail<<<ROWS_BN, 256, 0, stream>>>(z2b, c2c, w3, b3, pedge, dnode,
                                        p2dw, p2db, out0, out1);
}

// Round 19
// 157.092 us; speedup vs baseline: 1.0890x; 1.0890x over previous
//
#include <hip/hip_runtime.h>
#include <hip/hip_bf16.h>
#include <stdint.h>

#define N_ 160
#define B_ 16
#define C_ 64
#define S_ 80
#define TWO_C 128
#define BNN (B_*N_*N_)     // 409600 rows
#define ROWS_BN (B_*N_)    // 2560
#define RPB 4              // rows per k_fused block. Sweep: 2->91us, 4->87.4us, 8->102us. OPTIMUM.

typedef unsigned short u16;
using frag_ab = __attribute__((ext_vector_type(8))) short;   // 8 bf16
using frag_cd = __attribute__((ext_vector_type(4))) float;   // 4 f32

// hand-rolled RNE f32->bf16 — FASTER than native __float2bfloat16 on this
// kernel (r12 vs r13 A/B: 117 vs 149 us). Do not "modernize".
__device__ __forceinline__ u16 f2bf(float f) {
    union { float f; uint32_t u; } v; v.f = f;
    uint32_t u = v.u;
    return (u16)((u + 0x7FFFu + ((u >> 16) & 1u)) >> 16);
}
__device__ __forceinline__ float bf2f(u16 h) {
    union { uint32_t u; float f; } v; v.u = ((uint32_t)h) << 16;
    return v.f;
}
__device__ __forceinline__ float lrelu(float x) { return x >= 0.f ? x : 0.01f * x; }

// ---------------- closed-form BN1 stats: moments of v (BOTH calls) -----------
// k_prep folded into the first 64 blocks (w1/w2 -> bf16).
__global__ __launch_bounds__(256)
void k_mom(const float* __restrict__ v0, const float* __restrict__ v1,
           float* __restrict__ mom, float* __restrict__ s1p, float* __restrict__ s2p,
           const float* __restrict__ w1, const float* __restrict__ w2,
           u16* __restrict__ w1b, u16* __restrict__ w2b) {
    __shared__ __align__(16) float vl[32][64];
    const int gbid = blockIdx.x;
    const int call = gbid / 320;
    const int bid  = gbid % 320;
    const int ic  = bid % 5;
    const int c1g = (bid / 5) % 4;
    const int b   = bid / 20;
    const int t = threadIdx.x;
    if (gbid < 64) {                       // folded k_prep: 16384 converts
        int i = gbid * 256 + t;
        if (i < TWO_C * C_) w1b[i] = f2bf(w1[i]);
        else                w2b[i - TWO_C * C_] = f2bf(w2[i - TWO_C * C_]);
    }
    const float* v = call ? v1 : v0;
    const float* src = v + ((size_t)b * N_ + ic * 32) * C_;
    #pragma unroll
    for (int p = 0; p < 2; p++) {
        int idx = t + p * 256;
        *reinterpret_cast<float4*>(&vl[0][0] + (size_t)idx * 4) =
            *reinterpret_cast<const float4*>(src + (size_t)idx * 4);
    }
    __syncthreads();
    const int c1 = c1g * 16 + (t >> 4);
    const int c2b = (t & 15) * 4;
    float m2[4] = {0,0,0,0}, m21[4] = {0,0,0,0}, m22[4] = {0,0,0,0};
    for (int i = 0; i < 32; i++) {
        float x1 = vl[i][c1];
        #pragma unroll
        for (int q = 0; q < 4; q++) {
            float x2 = vl[i][c2b + q];
            float tt = x1 * x2;
            m2[q]  += tt;
            m21[q] += x1 * tt;
            m22[q] += tt * tt;
        }
    }
    const int pl = (t >> 4) * 64 + c2b;
    float* base = mom + (size_t)gbid * 3072;
    *reinterpret_cast<float4*>(base + pl)        = *reinterpret_cast<float4*>(m2);
    *reinterpret_cast<float4*>(base + 1024 + pl) = *reinterpret_cast<float4*>(m21);
    *reinterpret_cast<float4*>(base + 2048 + pl) = *reinterpret_cast<float4*>(m22);
    if (c1g == 0 && t < 64) {
        float s1 = 0.f, s2 = 0.f;
        for (int i = 0; i < 32; i++) { float x = vl[i][t]; s1 += x; s2 += x * x; }
        s1p[(size_t)(call * 80 + b * 5 + ic) * 64 + t] = s1;
        s2p[(size_t)(call * 80 + b * 5 + ic) * 64 + t] = s2;
    }
}

// S[c1,c2] + T1, both calls. grid 512 = call(2) x 256.
__global__ __launch_bounds__(256)
void k_S(const float* __restrict__ mom, const float* __restrict__ s1p,
         const float* __restrict__ s2p, float* __restrict__ Ssum,
         float* __restrict__ T1) {
    __shared__ float red[256];
    const int t = threadIdx.x;
    const int call = blockIdx.x / 256;
    const int lb = blockIdx.x % 256;
    const int pl = t >> 4, b = t & 15;
    const int pi = lb * 16 + pl;
    const int c1 = pi >> 6, c2 = pi & 63;
    const float* momc = mom + (size_t)call * 320 * 3072;
    const float* s1c = s1p + (size_t)call * 80 * 64;
    const float* s2c = s2p + (size_t)call * 80 * 64;
    const int bidA = (b * 4 + (c1 >> 4)) * 5;
    const int plA  = (c1 & 15) * 64 + c2;
    const int bidB = (b * 4 + (c2 >> 4)) * 5;
    const int plB  = (c2 & 15) * 64 + c1;
    float m2 = 0.f, m21 = 0.f, m22 = 0.f, m21T = 0.f;
    float s1c1 = 0.f, s1c2 = 0.f, s2c1 = 0.f, s2c2 = 0.f;
    #pragma unroll
    for (int ic = 0; ic < 5; ic++) {
        const float* base = momc + (size_t)(bidA + ic) * 3072;
        m2   += base[plA];
        m21  += base[1024 + plA];
        m22  += base[2048 + plA];
        m21T += momc[(size_t)(bidB + ic) * 3072 + 1024 + plB];
        s1c1 += s1c[(size_t)(b * 5 + ic) * 64 + c1];
        s1c2 += s1c[(size_t)(b * 5 + ic) * 64 + c2];
        s2c1 += s2c[(size_t)(b * 5 + ic) * 64 + c1];
        s2c2 += s2c[(size_t)(b * 5 + ic) * 64 + c2];
    }
    float S = 2.f*(float)N_*m22 + 2.f*s2c1*s2c2 + 4.f*m2*m2
            - 4.f*m21*s1c2 - 4.f*m21T*s1c1;
    red[t] = S; __syncthreads();
    #pragma unroll
    for (int off = 8; off; off >>= 1) {
        if (b < off) red[t] += red[t + off];
        __syncthreads();
    }
    if (b == 0) Ssum[call * 4096 + pi] = red[t];
    if (lb < 4) {
        float tv = 2.f*(float)N_*s2c2 - 2.f*s1c2*s1c2;
        __syncthreads();
        red[t] = tv; __syncthreads();
        #pragma unroll
        for (int off = 8; off; off >>= 1) {
            if (b < off) red[t] += red[t + off];
            __syncthreads();
        }
        if (b == 0) T1[call * 64 + pi] = red[t];
    }
}

// per-o BN1 constants, both calls. grid 256 = call(2) x o(128).
__global__ __launch_bounds__(64)
void k_bn1const(const float* __restrict__ Ssum, const float* __restrict__ T1,
                const float* __restrict__ w1, const float* __restrict__ g1,
                const float* __restrict__ b1, float* __restrict__ c1c) {
    const int call = blockIdx.x >> 7;
    const int o = blockIdx.x & 127;
    const int c1 = threadIdx.x;
    const float* Ss = Ssum + call * 4096;
    const float* T1c = T1 + call * 64;
    const float* wrow = w1 + (size_t)o * 64;
    float wc1 = wrow[c1];
    float acc = 0.f;
    for (int c2 = 0; c2 < 64; c2++)
        acc += wrow[c2] * Ss[c1 * 64 + c2];
    float qf = wc1 * acc;
    float mn = wc1 * T1c[c1];
    #pragma unroll
    for (int off = 32; off; off >>= 1) {
        qf += __shfl_xor(qf, off, 64);
        mn += __shfl_xor(mn, off, 64);
    }
    if (c1 == 0) {
        const float inv = 1.f / (float)BNN;
        float mean = mn * inv;
        float var  = qf * inv - mean * mean;
        float a = g1[o] * rsqrtf(var + 1e-5f);
        c1c[call * 256 + o] = a;
        c1c[call * 256 + 128 + o] = b1[o] - mean * a;
    }
}

// ---------------- fused heavy stage: r12 inner structure, RPB rows per block -
// grid = 2*ROWS_BN/RPB. Inner 3-barrier j-tile loop is the verified r12
// pipeline; outer rr loop amortizes bfrag/c1c setup RPB x and divides the
// block-cohort count. Pending-store keeps store/compute overlap across row
// boundaries (same 2-barrier hazard separation). Row quads stay in one batch.
__global__ __launch_bounds__(256)
void k_fused(const float* __restrict__ v0, const float* __restrict__ v1,
             const u16* __restrict__ w1b, const float* __restrict__ c1c_all,
             const u16* __restrict__ w2b, u16* __restrict__ z2b_all,
             float* __restrict__ partials_all) {
    __shared__ __align__(16) u16 simT[32 * 64];
    __shared__ __align__(16) u16 h1T[32 * 128];
    __shared__ __align__(16) u16 z2T[32 * 64];
    __shared__ float sb_s[4][64];
    __shared__ float sb_ss[4][64];
    const int gbid = blockIdx.x;
    const int call = gbid / (ROWS_BN / RPB);
    const int ri0 = (gbid % (ROWS_BN / RPB)) * RPB;
    const float* __restrict__ v = call ? v1 : v0;
    const float* __restrict__ c1c = c1c_all + call * 256;
    u16* __restrict__ z2b = z2b_all + (size_t)call * BNN * C_;
    float* __restrict__ partials = partials_all;  // indexed by gbid

    const int t = threadIdx.x;
    const int bb = ri0 / N_;
    const int w = t >> 6, lane = t & 63;
    const int l15 = lane & 15, kgrp = lane >> 4, k0 = kgrp * 8;
    const int jt16 = w & 1;           // GEMM1 row-half
    const int rh = w >> 1, q = w & 1; // GEMM2 row-half / col-half
    const int obase = rh * 64;        // GEMM1 o-quadrant

    const int jj = t >> 3, c0 = (t & 7) * 8;
    const float* __restrict__ vrow = v + (size_t)bb * N_ * C_;

    frag_ab bfrag[4][2];
    float cAr[4], cBr[4];
    #pragma unroll
    for (int tt = 0; tt < 4; tt++) {
        int o = obase + tt * 16 + l15;
        #pragma unroll
        for (int kk = 0; kk < 2; kk++)
            bfrag[tt][kk] = *reinterpret_cast<const frag_ab*>(w1b + o * 64 + kk * 32 + k0);
        cAr[tt] = c1c[o];
        cBr[tt] = c1c[128 + o];
    }

    float s_l[2] = {0.f, 0.f}, ss_l[2] = {0.f, 0.f};
    size_t pend_rowb = 0;
    bool pend = false;

    for (int rr = 0; rr < RPB; rr++) {
        const int ri = ri0 + rr;
        const float* __restrict__ vi = v + (size_t)ri * C_;
        float fi[8] __attribute__((aligned(16)));
        *reinterpret_cast<float4*>(&fi[0]) = *reinterpret_cast<const float4*>(vi + c0);
        *reinterpret_cast<float4*>(&fi[4]) = *reinterpret_cast<const float4*>(vi + c0 + 4);
        float fj[8] __attribute__((aligned(16)));
        {
            const float* vj = vrow + (size_t)jj * C_ + c0;
            *reinterpret_cast<float4*>(&fj[0]) = *reinterpret_cast<const float4*>(vj);
            *reinterpret_cast<float4*>(&fj[4]) = *reinterpret_cast<const float4*>(vj + 4);
        }

        for (int jt = 0; jt < 5; jt++) {
            // ---- P1: coalesced store of pending z2 tile + build sim tile ----
            if (pend) {
                int idx = (jj * 64 + c0) ^ ((jj & 7) << 3);
                frag_ab zz = *reinterpret_cast<const frag_ab*>(&z2T[idx]);
                *reinterpret_cast<frag_ab*>(z2b + (pend_rowb + jj) * C_ + c0) = zz;
            }
            {
                frag_ab pack;
                #pragma unroll
                for (int p8 = 0; p8 < 8; p8++) {
                    float d = fi[p8] - fj[p8];
                    pack[p8] = (short)f2bf(d * d);
                }
                int idx = (jj * 64 + c0) ^ ((jj & 7) << 3);
                *reinterpret_cast<frag_ab*>(&simT[idx]) = pack;
            }
            __syncthreads();                                   // bar1

            // ---- P2: GEMM1 + BN1/lrelu pack -> h1T ----
            frag_cd acc1[4];
            #pragma unroll
            for (int tt = 0; tt < 4; tt++) acc1[tt] = frag_cd{0.f, 0.f, 0.f, 0.f};
            #pragma unroll
            for (int kk = 0; kk < 2; kk++) {
                const int rj = jt16 * 16 + l15;
                const int idx = (rj * 64 + kk * 32 + k0) ^ ((rj & 7) << 3);
                frag_ab a = *reinterpret_cast<const frag_ab*>(&simT[idx]);
                #pragma unroll
                for (int tt = 0; tt < 4; tt++)
                    acc1[tt] = __builtin_amdgcn_mfma_f32_16x16x32_bf16(a, bfrag[tt][kk], acc1[tt], 0, 0, 0);
            }
            #pragma unroll
            for (int tt = 0; tt < 4; tt++) {
                const int o = obase + tt * 16 + l15;
                #pragma unroll
                for (int r = 0; r < 4; r++) {
                    const int row = jt16 * 16 + kgrp * 4 + r;
                    float hv = lrelu(acc1[tt][r] * cAr[tt] + cBr[tt]);
                    h1T[(row * 128 + o) ^ ((row & 7) << 3)] = f2bf(hv);
                }
            }
            __syncthreads();                                   // bar2

            // ---- P3: prefetch next fj, GEMM2, pack z2T, stats ----
            if (jt < 4) {
                const float* vj = vrow + ((size_t)(jt + 1) * 32 + jj) * C_ + c0;
                *reinterpret_cast<float4*>(&fj[0]) = *reinterpret_cast<const float4*>(vj);
                *reinterpret_cast<float4*>(&fj[4]) = *reinterpret_cast<const float4*>(vj + 4);
            }
            frag_cd acc2[2];
            acc2[0] = frag_cd{0.f,0.f,0.f,0.f}; acc2[1] = frag_cd{0.f,0.f,0.f,0.f};
            #pragma unroll
            for (int kk = 0; kk < 4; kk++) {
                const int rrr = rh * 16 + l15;
                const int idx = (rrr * 128 + kk * 32 + k0) ^ ((rrr & 7) << 3);
                frag_ab a = *reinterpret_cast<const frag_ab*>(&h1T[idx]);
                #pragma unroll
                for (int tt = 0; tt < 2; tt++) {
                    const int p = q * 32 + tt * 16 + l15;
                    frag_ab bfr = *reinterpret_cast<const frag_ab*>(w2b + (size_t)p * 128 + kk * 32 + k0);
                    acc2[tt] = __builtin_amdgcn_mfma_f32_16x16x32_bf16(a, bfr, acc2[tt], 0, 0, 0);
                }
            }
            #pragma unroll
            for (int tt = 0; tt < 2; tt++) {
                const int p = q * 32 + tt * 16 + l15;
                #pragma unroll
                for (int r = 0; r < 4; r++) {
                    const int row = rh * 16 + kgrp * 4 + r;
                    float val = acc2[tt][r];
                    z2T[(row * 64 + p) ^ ((row & 7) << 3)] = f2bf(val);
                    s_l[tt] += val; ss_l[tt] += val * val;
                }
            }
            pend_rowb = (size_t)ri * N_ + (size_t)jt * 32;
            pend = true;
            __syncthreads();                                   // bar3
        }
    }

    // ---- epilogue: store last z2 tile ----
    {
        int idx = (jj * 64 + c0) ^ ((jj & 7) << 3);
        frag_ab zz = *reinterpret_cast<const frag_ab*>(&z2T[idx]);
        *reinterpret_cast<frag_ab*>(z2b + (pend_rowb + jj) * C_ + c0) = zz;
    }
    // ---- stats reduce -> per-block contiguous partials (indexed by gbid) ----
    #pragma unroll
    for (int tt = 0; tt < 2; tt++) {
        s_l[tt]  += __shfl_xor(s_l[tt], 16, 64);  s_l[tt]  += __shfl_xor(s_l[tt], 32, 64);
        ss_l[tt] += __shfl_xor(ss_l[tt], 16, 64); ss_l[tt] += __shfl_xor(ss_l[tt], 32, 64);
    }
    if (lane < 16) {
        #pragma unroll
        for (int tt = 0; tt < 2; tt++) {
            const int p = q * 32 + tt * 16 + l15;
            sb_s[w][p]  = s_l[tt];
            sb_ss[w][p] = ss_l[tt];
        }
    }
    __syncthreads();
    if (t < 64) {
        const int qq = t >> 5;
        partials[(size_t)gbid * 128 + t]      = sb_s[qq][t]  + sb_s[qq + 2][t];
        partials[(size_t)gbid * 128 + 64 + t] = sb_ss[qq][t] + sb_ss[qq + 2][t];
    }
}

// reduce partials + BN2 consts, both calls: grid 128 = call(2) x c(64)
// partials are per-k_fused-block (ROWS_BN/RPB blocks per call).
__global__ __launch_bounds__(256)
void k_reduce_bn2(const float* __restrict__ partials_all, const float* __restrict__ g2,
                  const float* __restrict__ b2, float* __restrict__ c2c) {
    const int call = blockIdx.x >> 6;
    const int c = blockIdx.x & 63;
    const int t = threadIdx.x;
    const float* partials = partials_all + (size_t)call * (ROWS_BN / RPB) * 128;
    float s = 0.f, ss = 0.f;
    for (int b = t; b < ROWS_BN / RPB; b += 256) {
        s  += partials[(size_t)b * 128 + c];
        ss += partials[(size_t)b * 128 + 64 + c];
    }
    __shared__ float l1[256], l2[256];
    l1[t] = s; l2[t] = ss; __syncthreads();
    for (int off = 128; off; off >>= 1) {
        if (t < off) { l1[t] += l1[t + off]; l2[t] += l2[t + off]; }
        __syncthreads();
    }
    if (t == 0) {
        const float inv = 1.f / (float)BNN;
        float mean = l1[0] * inv;
        float var  = l2[0] * inv - mean * mean;
        float a = g2[c] * rsqrtf(var + 1e-5f);
        c2c[call * 128 + c] = a;
        c2c[call * 128 + 64 + c] = b2[c] - mean * a;
    }
}

// ---------------- ONE tail kernel: e0,e1 (parallel) + edge chain + p2d -------
__device__ __forceinline__ float block_sum(float v, float* lds) {
    #pragma unroll
    for (int off = 32; off; off >>= 1) v += __shfl_xor(v, off, 64);
    __syncthreads();
    if ((threadIdx.x & 63) == 0) lds[threadIdx.x >> 6] = v;
    __syncthreads();
    return lds[0] + lds[1] + lds[2] + lds[3];
}
__device__ __forceinline__ float edge_renorm(float e, float ep, bool diag, bool valid,
                                             float* lds4) {
    float epm = diag ? 0.f : ep;
    float rs = block_sum(epm, lds4);
    float x = e * epm;
    float s = block_sum(fabsf(x), lds4);
    x = x / fmaxf(s, 1e-12f) * rs;
    x += (diag ? 1.f : 0.f) + 1e-6f;
    float tot = block_sum(valid ? x : 0.f, lds4);
    return x / tot;
}

__global__ __launch_bounds__(256)
void k_tail(const u16* __restrict__ z2b_all, const float* __restrict__ c2c,
            const float* __restrict__ w3, const float* __restrict__ b3,
            const float* __restrict__ pedge, const float* __restrict__ dnode,
            const float* __restrict__ p2dw, const float* __restrict__ p2db,
            float* __restrict__ out0, float* __restrict__ out1) {
    __shared__ float cs[320];          // c2c[0..255] | w3[256..319]
    __shared__ float e0l[N_], e1l[N_];
    __shared__ float lds4[4];
    __shared__ float xl[2 * S_];
    const int r = blockIdx.x;          // b*N + i
    const int t = threadIdx.x;
    const float bb3 = b3[0];

    cs[t] = (t < 256) ? c2c[t] : 0.f;
    if (t < 64) cs[256 + t] = w3[t];
    __syncthreads();

    // ---- phase A: e0/e1 rows, 8 threads per j, 32 j per pass ----
    const int jloc = t >> 3, cA0 = (t & 7) * 8;
    #pragma unroll
    for (int pass = 0; pass < 5; pass++) {
        const int j = pass * 32 + jloc;
        const u16* zr0 = z2b_all + ((size_t)r * N_ + j) * C_ + cA0;
        const u16* zr1 = zr0 + (size_t)BNN * C_;
        frag_ab z0 = *reinterpret_cast<const frag_ab*>(zr0);
        frag_ab z1 = *reinterpret_cast<const frag_ab*>(zr1);
        float a0 = 0.f, a1 = 0.f;
        #pragma unroll
        for (int qi = 0; qi < 8; qi++) {
            const int c = cA0 + qi;
            a0 += lrelu(bf2f((u16)z0[qi]) * cs[c]       + cs[64 + c])  * cs[256 + c];
            a1 += lrelu(bf2f((u16)z1[qi]) * cs[128 + c] + cs[192 + c]) * cs[256 + c];
        }
        a0 += __shfl_xor(a0, 1, 64); a0 += __shfl_xor(a0, 2, 64); a0 += __shfl_xor(a0, 4, 64);
        a1 += __shfl_xor(a1, 1, 64); a1 += __shfl_xor(a1, 2, 64); a1 += __shfl_xor(a1, 4, 64);
        if ((t & 7) == 0) {
            e0l[j] = 1.f / (1.f + __expf(-(a0 + bb3)));
            e1l[j] = 1.f / (1.f + __expf(-(a1 + bb3)));
        }
    }
    __syncthreads();

    // ---- phase B: edge chain + p2d (row-local) ----
    const bool valid = t < N_;
    const int iLoc = r % N_;
    const bool diag = (t == iLoc);
    float e0 = valid ? e0l[t] : 0.f;
    float e1 = valid ? e1l[t] : 0.f;
    float pedge_v = valid ? pedge[(size_t)r * N_ + t] : 0.f;

    float pe0 = edge_renorm(e0, pedge_v, diag, valid, lds4);   // initial edge
    float pe1 = edge_renorm(e1, pe0,     diag, valid, lds4);   // gen0 edge

    __syncthreads();
    if (t < S_) { xl[t] = pe1; xl[S_ + t] = dnode[(size_t)r * S_ + t]; }
    __syncthreads();
    float dn1 = 0.f;
    if (t < S_) {
        float acc = p2db[t];
        const float* wr = p2dw + (size_t)t * (2 * S_);
        #pragma unroll 4
        for (int k = 0; k < 2 * S_; k++) acc += xl[k] * wr[k];
        dn1 = lrelu(acc);
        out0[(size_t)r * S_ + t] = dn1;
    }

    float pe2 = edge_renorm(e1, pe1, diag, valid, lds4);       // gen1 edge

    __syncthreads();
    if (t < S_) { xl[t] = pe2; xl[S_ + t] = dn1; }
    __syncthreads();
    if (t < S_) {
        float acc = p2db[S_ + t];
        const float* wr = p2dw + (size_t)(S_ + t) * (2 * S_);
        #pragma unroll 4
        for (int k = 0; k < 2 * S_; k++) acc += xl[k] * wr[k];
        out1[(size_t)r * S_ + t] = lrelu(acc);
    }
}

// ---------------- launch -----------------------------------------------------
extern "C" void kernel_launch(void* const* d_in, const int* in_sizes, int n_in,
                              void* d_out, int out_size, void* d_ws, size_t ws_size,
                              hipStream_t stream) {
    const float* middle = (const float*)d_in[0];
    const float* point  = (const float*)d_in[1];
    const float* dnode  = (const float*)d_in[2];
    // d_in[3] = distribution_edge: unused by the reference forward
    const float* pedge  = (const float*)d_in[4];
    const float* w1 = (const float*)d_in[5];
    const float* g1 = (const float*)d_in[6];
    const float* b1 = (const float*)d_in[7];
    const float* w2 = (const float*)d_in[8];
    const float* g2 = (const float*)d_in[9];
    const float* b2 = (const float*)d_in[10];
    const float* w3 = (const float*)d_in[11];
    const float* b3 = (const float*)d_in[12];
    const float* p2dw = (const float*)d_in[13];
    const float* p2db = (const float*)d_in[14];

    float* out0 = (float*)d_out;
    float* out1 = out0 + (size_t)ROWS_BN * S_;

    char* ws = (char*)d_ws;
    size_t off = 0;
    auto alloc = [&](size_t bytes) -> char* {
        char* p = ws + off;
        off += (bytes + 255) & ~(size_t)255;
        return p;
    };
    u16*   z2b      = (u16*)  alloc((size_t)2 * BNN * C_ * 2);       // 104.9 MB
    u16*   w1b      = (u16*)  alloc(TWO_C * C_ * 2);
    u16*   w2b      = (u16*)  alloc(C_ * TWO_C * 2);
    float* partials = (float*)alloc((size_t)(2 * ROWS_BN / RPB) * 128 * 4);
    float* mom      = (float*)alloc((size_t)2 * 320 * 3072 * 4);     // 7.86 MB
    float* s1p      = (float*)alloc((size_t)2 * 80 * 64 * 4);
    float* s2p      = (float*)alloc((size_t)2 * 80 * 64 * 4);
    float* Ssum     = (float*)alloc(2 * 4096 * 4);
    float* T1       = (float*)alloc(2 * 64 * 4);
    float* c1c      = (float*)alloc(2 * 256 * 4);
    float* c2c      = (float*)alloc(2 * 128 * 4);

    // call0 = middle_node, call1 = point_node; e(point) reused for both gens.
    k_mom<<<640, 256, 0, stream>>>(middle, point, mom, s1p, s2p, w1, w2, w1b, w2b);
    k_S<<<512, 256, 0, stream>>>(mom, s1p, s2p, Ssum, T1);
    k_bn1const<<<256, 64, 0, stream>>>(Ssum, T1, w1, g1, b1, c1c);
    k_fused<<<2 * ROWS_BN / RPB, 256, 0, stream>>>(middle, point, w1b, c1c, w2b, z2b, partials);
    k_reduce_bn2<<<128, 256, 0, stream>>>(partials, g2, b2, c2c);
    k_tail<<<ROWS_BN, 256, 0, stream>>>(z2b, c2c, w3, b3, pedge, dnode,
                                        p2dw, p2db, out0, out1);
}